// Round 15
// baseline (550.869 us; speedup 1.0000x reference)
//
#include <hip/hip_runtime.h>
#include <hip/hip_bf16.h>
#include <math.h>

#define AS1 __attribute__((address_space(1)))
#define AS3 __attribute__((address_space(3)))

typedef __attribute__((ext_vector_type(8))) short bf16x8;
typedef __attribute__((ext_vector_type(4))) float f32x4;
typedef __hip_bfloat16 bf16;

namespace {
constexpr int kBatch = 4, kS = 2048, kD = 512;
constexpr int kRows = kBatch * kS;   // 8192
constexpr int kTopK = 64;
constexpr int kSel = 65;             // select 65, refine the 64/65 boundary
}

__device__ __forceinline__ void async16(void* lds, const void* g) {
  __builtin_amdgcn_global_load_lds((AS1 void*)g, (AS3 void*)lds, 16, 0, 0);
}

template<int N> __device__ __forceinline__ void wait_vm() {
  if constexpr (N == 0) asm volatile("s_waitcnt vmcnt(0)" ::: "memory");
  else if constexpr (N == 3) asm volatile("s_waitcnt vmcnt(3)" ::: "memory");
  else if constexpr (N == 4) asm volatile("s_waitcnt vmcnt(4)" ::: "memory");
  else if constexpr (N == 6) asm volatile("s_waitcnt vmcnt(6)" ::: "memory");
  else if constexpr (N == 9) asm volatile("s_waitcnt vmcnt(9)" ::: "memory");
  else static_assert(N == 0, "unsupported vmcnt");
}

// ---------- fp32 -> bf16 h/m/l 3-way split ----------
__global__ __launch_bounds__(256) void split3(
    const float* __restrict__ in, bf16* __restrict__ h, bf16* __restrict__ m,
    bf16* __restrict__ l, int n) {
  int i = blockIdx.x * 256 + threadIdx.x;
  const int stride = gridDim.x * 256;
  for (; i < n; i += stride) {
    const float x = in[i];
    const bf16 hh = __float2bfloat16(x);
    const float r = x - __bfloat162float(hh);
    const bf16 mm = __float2bfloat16(r);
    const float r2 = r - __bfloat162float(mm);
    h[i] = hh; m[i] = mm; l[i] = __float2bfloat16(r2);
  }
}

// fused 2-weight split, h/m only (Wq, Wk in one launch; l not needed)
__global__ __launch_bounds__(256) void split2x2(
    const float* __restrict__ w0, bf16* __restrict__ h0, bf16* __restrict__ m0,
    const float* __restrict__ w1, bf16* __restrict__ h1, bf16* __restrict__ m1,
    int n) {
  const float* in = blockIdx.y ? w1 : w0;
  bf16* h = blockIdx.y ? h1 : h0;
  bf16* m = blockIdx.y ? m1 : m0;
  int i = blockIdx.x * 256 + threadIdx.x;
  const int stride = gridDim.x * 256;
  for (; i < n; i += stride) {
    const float x = in[i];
    const bf16 hh = __float2bfloat16(x);
    h[i] = hh;
    m[i] = __float2bfloat16(x - __bfloat162float(hh));
  }
}

// ---------- Mh = bf16(Wo @ Wv) ----------
__global__ __launch_bounds__(256) void precompute_M(
    const float* __restrict__ Wo, const float* __restrict__ Wv, bf16* __restrict__ Mh) {
  __shared__ float sWo[64][65];
  __shared__ float sWv[64][65];
  const int e0 = blockIdx.y * 64, f0 = blockIdx.x * 64;
  const int tr = threadIdx.x >> 4, tc = threadIdx.x & 15;
  float acc[4][4] = {};
  for (int d0 = 0; d0 < kD; d0 += 64) {
    for (int i = threadIdx.x; i < 64 * 64; i += 256) {
      const int r = i >> 6, c = i & 63;
      sWo[r][c] = Wo[(long)(e0 + r) * kD + d0 + c];
      sWv[r][c] = Wv[(long)(d0 + r) * kD + f0 + c];
    }
    __syncthreads();
    for (int d = 0; d < 64; ++d) {
      float a[4], b[4];
#pragma unroll
      for (int i = 0; i < 4; ++i) a[i] = sWo[tr * 4 + i][d];
#pragma unroll
      for (int j = 0; j < 4; ++j) b[j] = sWv[d][tc * 4 + j];
#pragma unroll
      for (int i = 0; i < 4; ++i)
#pragma unroll
        for (int j = 0; j < 4; ++j) acc[i][j] = fmaf(a[i], b[j], acc[i][j]);
    }
    __syncthreads();
  }
#pragma unroll
  for (int i = 0; i < 4; ++i)
#pragma unroll
    for (int j = 0; j < 4; ++j)
      Mh[(long)(e0 + tr * 4 + i) * kD + f0 + tc * 4 + j] = __float2bfloat16(acc[i][j]);
}

// ---------- cb = Wo @ bv : one wave per output element, coalesced ----------
__global__ __launch_bounds__(64) void precompute_cb(
    const float* __restrict__ Wo, const float* __restrict__ bv, float* __restrict__ cb) {
  const int e = blockIdx.x;
  const int ln = threadIdx.x;
  float s = 0.f;
  for (int d = ln; d < kD; d += 64) s = fmaf(Wo[(long)e * kD + d], bv[d], s);
#pragma unroll
  for (int off = 32; off; off >>= 1) s += __shfl_down(s, off);
  if (ln == 0) cb[e] = s;
}

// ---------- pipelined C[M,N] = scale*(A @ B^T) + bias, split-bf16 precision ----------
// PROVEN structure (rounds 5/7/8/9/13/14, passed post-timing): dbuf LDS + counted
// vmcnt, one STAGE + one monolithic COMPUTE per K-step, two raw barriers.
// OUTMODE 0: fp32 C; 1: h/m/l out; 2: h/m out; 3: h out. BIASROW: bias[row].
template<int OUTMODE, int NPROD, int BM, int BN, int WAVES_M, int WAVES_N, bool BIASROW>
__global__ __launch_bounds__(64 * WAVES_M * WAVES_N, 2) void gemm_pipe(
    const bf16* __restrict__ Ah, const bf16* __restrict__ Am, const bf16* __restrict__ Al,
    const bf16* __restrict__ Bh, const bf16* __restrict__ Bm, const bf16* __restrict__ Bl,
    float* __restrict__ C, bf16* __restrict__ Ch, bf16* __restrict__ Cm, bf16* __restrict__ Cl,
    const float* __restrict__ bias, float scale, int N, int K, int lda, int ldb,
    long batchA, long batchB, long batchC) {
  constexpr int NP = (NPROD == 6) ? 3 : (NPROD == 3) ? 2 : 1;
  constexpr int T = 64 * WAVES_M * WAVES_N;
  constexpr int WM = BM / WAVES_M, WN = BN / WAVES_N;
  constexpr int FI = WM / 16, FJ = WN / 16;
  constexpr int ABYTES = BM * 64, BBYTES = BN * 64;
  constexpr int HALF = NP * (ABYTES + BBYTES);
  constexpr int SPAN = T * 16;
  constexpr int CALLS = HALF / SPAN;
  static_assert(HALF % SPAN == 0, "staging must be whole call-spans");
  extern __shared__ char smem[];

  const int t = threadIdx.x;
  const int wi = t >> 6, ln = t & 63;
  const int wr = wi / WAVES_N, wc = wi % WAVES_N;

  int bx, by, bz;
  {
    const int F = blockIdx.x + gridDim.x * (blockIdx.y + gridDim.y * blockIdx.z);
    const int cpx = (gridDim.x * gridDim.y * gridDim.z) >> 3;
    const int L = (F & 7) * cpx + (F >> 3);
    bx = L % gridDim.x;
    const int r = L / gridDim.x;
    by = r % gridDim.y; bz = r / gridDim.y;
  }
  const int m0 = by * BM, n0 = bx * BN;
  const long zA = (long)bz * batchA;
  const long zB = (long)bz * batchB;
  const long zC = (long)bz * batchC;

  const bf16* gp[CALLS];
#pragma unroll
  for (int q = 0; q < CALLS; ++q) {
    const int o = q * SPAN + t * 16;
    const bf16* base; long rbase; int local; int ld;
    if (o < NP * ABYTES) {
      const int p = o / ABYTES; local = o % ABYTES;
      base = (p == 0) ? Ah : (p == 1) ? Am : Al;
      rbase = zA + (long)m0 * lda; ld = lda;
    } else {
      const int o2 = o - NP * ABYTES;
      const int p = o2 / BBYTES; local = o2 % BBYTES;
      base = (p == 0) ? Bh : (p == 1) ? Bm : Bl;
      rbase = zB + (long)n0 * ldb; ld = ldb;
    }
    const int s = local >> 7;
    const int pc = (local >> 4) & 7;
    const int lc = pc ^ (s & 7);
    const int row = 2 * s + (lc >> 2);
    const int ke = (lc & 3) << 3;
    gp[q] = base + rbase + (long)row * ld + ke;
  }
  const int lofs = wi * 1024;

  const int fr = ln & 15, cc = ln >> 4;
  const int c2 = ((fr & 1) << 2) | cc;
  int aoff[FI], boff[FJ];
#pragma unroll
  for (int i = 0; i < FI; ++i) {
    const int s = (wr * WM + i * 16 + fr) >> 1;
    aoff[i] = s * 128 + ((c2 ^ (s & 7)) << 4);
  }
#pragma unroll
  for (int j = 0; j < FJ; ++j) {
    const int s = (wc * WN + j * 16 + fr) >> 1;
    boff[j] = s * 128 + ((c2 ^ (s & 7)) << 4);
  }

  f32x4 acc1[FI][FJ] = {}, acc2[FI][FJ] = {};

  auto STAGE = [&](int buf, int kt) {
#pragma unroll
    for (int q = 0; q < CALLS; ++q)
      async16(smem + buf * HALF + q * SPAN + lofs, gp[q] + kt);
  };

  auto COMPUTE = [&](const char* rb) {
    bf16x8 AH[FI], BH[FJ], AX[FI], BX[FJ];
#pragma unroll
    for (int i = 0; i < FI; ++i) AH[i] = *(const bf16x8*)(rb + aoff[i]);
#pragma unroll
    for (int j = 0; j < FJ; ++j) BH[j] = *(const bf16x8*)(rb + NP * ABYTES + boff[j]);
#pragma unroll
    for (int i = 0; i < FI; ++i)
#pragma unroll
      for (int j = 0; j < FJ; ++j)
        acc1[i][j] = __builtin_amdgcn_mfma_f32_16x16x32_bf16(AH[i], BH[j], acc1[i][j], 0, 0, 0);
    if constexpr (NPROD == 6) {
#pragma unroll
      for (int i = 0; i < FI; ++i) AX[i] = *(const bf16x8*)(rb + 2 * ABYTES + aoff[i]);
#pragma unroll
      for (int j = 0; j < FJ; ++j) BX[j] = *(const bf16x8*)(rb + NP * ABYTES + 2 * BBYTES + boff[j]);
#pragma unroll
      for (int i = 0; i < FI; ++i)
#pragma unroll
        for (int j = 0; j < FJ; ++j) {
          acc2[i][j] = __builtin_amdgcn_mfma_f32_16x16x32_bf16(AH[i], BX[j], acc2[i][j], 0, 0, 0);
          acc2[i][j] = __builtin_amdgcn_mfma_f32_16x16x32_bf16(AX[i], BH[j], acc2[i][j], 0, 0, 0);
        }
    }
    if constexpr (NPROD >= 3) {
#pragma unroll
      for (int i = 0; i < FI; ++i) AX[i] = *(const bf16x8*)(rb + 1 * ABYTES + aoff[i]);
#pragma unroll
      for (int j = 0; j < FJ; ++j) BX[j] = *(const bf16x8*)(rb + NP * ABYTES + 1 * BBYTES + boff[j]);
#pragma unroll
      for (int i = 0; i < FI; ++i)
#pragma unroll
        for (int j = 0; j < FJ; ++j) {
          acc2[i][j] = __builtin_amdgcn_mfma_f32_16x16x32_bf16(AH[i], BX[j], acc2[i][j], 0, 0, 0);
          acc2[i][j] = __builtin_amdgcn_mfma_f32_16x16x32_bf16(AX[i], BH[j], acc2[i][j], 0, 0, 0);
          if constexpr (NPROD == 6)
            acc2[i][j] = __builtin_amdgcn_mfma_f32_16x16x32_bf16(AX[i], BX[j], acc2[i][j], 0, 0, 0);
        }
    }
  };

  STAGE(0, 0);
  int cur = 0;
  for (int kt = 32; kt < K; kt += 32) {
    STAGE(cur ^ 1, kt);
    wait_vm<CALLS>();
    __builtin_amdgcn_s_barrier();
    COMPUTE(smem + cur * HALF);
    asm volatile("s_waitcnt lgkmcnt(0)" ::: "memory");
    __builtin_amdgcn_s_barrier();
    cur ^= 1;
  }
  wait_vm<0>();
  __builtin_amdgcn_s_barrier();
  COMPUTE(smem + cur * HALF);

  const int fc = ln & 15;
  const int fr4 = (ln >> 4) << 2;
#pragma unroll
  for (int i = 0; i < FI; ++i) {
    const int rbase = m0 + wr * WM + i * 16 + fr4;
#pragma unroll
    for (int j = 0; j < FJ; ++j) {
      const int c = n0 + wc * WN + j * 16 + fc;
#pragma unroll
      for (int q = 0; q < 4; ++q) {
        const float bb = bias ? (BIASROW ? bias[rbase + q] : bias[c]) : 0.0f;
        const float val = (acc1[i][j][q] + acc2[i][j][q]) * scale + bb;
        const long off = zC + (long)(rbase + q) * N + c;
        if constexpr (OUTMODE == 0) {
          C[off] = val;
        } else if constexpr (OUTMODE == 1) {
          const bf16 h = __float2bfloat16(val);
          const float r = val - __bfloat162float(h);
          const bf16 m = __float2bfloat16(r);
          Ch[off] = h; Cm[off] = m;
          Cl[off] = __float2bfloat16(r - __bfloat162float(m));
        } else if constexpr (OUTMODE == 2) {
          const bf16 h = __float2bfloat16(val);
          Ch[off] = h;
          Cm[off] = __float2bfloat16(val - __bfloat162float(h));
        } else {
          Ch[off] = __float2bfloat16(val);
        }
      }
    }
  }
}

// ---------- radix-select top-65 + true-fp64 boundary refine + softmax + attn ----------
__device__ __forceinline__ unsigned f2key(float f) {
  const unsigned u = __float_as_uint(f);
  return (u & 0x80000000u) ? ~u : (u | 0x80000000u);
}
__device__ __forceinline__ bool worse(float av, int ac, float bv, int bc) {
  return (av < bv) || (av == bv && ac > bc);
}

__global__ __launch_bounds__(256) void topk_kernel(
    const float* __restrict__ scores,
    const float* __restrict__ x, const float* __restrict__ Wq, const float* __restrict__ bq,
    const float* __restrict__ Wk, const float* __restrict__ bk,
    float* __restrict__ attn, bf16* __restrict__ attnh) {
  const int row = blockIdx.x;  // 0..8191
  const int t = threadIdx.x, ln = t & 63, w = t >> 6;
  const float* srow = scores + (long)row * kS;

  __shared__ __align__(16) unsigned hist[2048];
  __shared__ float s_wval[kSel];
  __shared__ int s_wcol[kSel];
  __shared__ float s_kv[kTopK];
  __shared__ int s_kc[kTopK];
  __shared__ unsigned wsum[4];
  __shared__ int s_cut, s_ngt, s_nw, s_ntie;
  __shared__ int s_tie[128];
  __shared__ float s_tieval;
  __shared__ int s_c0, s_c1, s_excl, s_slot;
  __shared__ float s_gap;
  __shared__ float sxq[kD], sx0[kD], sx1[kD];
  __shared__ double rd0[4], rd1[4];

  if (t == 0) { s_nw = 0; s_ntie = 0; }

  float val[8]; unsigned key[8];
  {
    const float4 q0 = ((const float4*)srow)[t];
    const float4 q1 = ((const float4*)srow)[t + 256];
    val[0] = q0.x; val[1] = q0.y; val[2] = q0.z; val[3] = q0.w;
    val[4] = q1.x; val[5] = q1.y; val[6] = q1.z; val[7] = q1.w;
  }
#pragma unroll
  for (int j = 0; j < 8; ++j) key[j] = f2key(val[j]);

  unsigned alive = 0xFFu, winner = 0u;
  int rem = kSel, done = 0;

  for (int level = 0; level < 3; ++level) {
    const int shift = (level == 0) ? 21 : (level == 1) ? 10 : 0;
    const unsigned bmask = (level == 2) ? 0x3FFu : 0x7FFu;
    for (int i = t; i < 2048; i += 256) hist[i] = 0u;
    __syncthreads();
#pragma unroll
    for (int j = 0; j < 8; ++j)
      if (alive & (1u << j)) atomicAdd(&hist[(key[j] >> shift) & bmask], 1u);
    __syncthreads();

    unsigned h[8]; unsigned ts = 0u;
#pragma unroll
    for (int b = 0; b < 8; ++b) { h[b] = hist[8 * t + b]; ts += h[b]; }
    unsigned ss = ts;
#pragma unroll
    for (int off = 1; off < 64; off <<= 1) {
      const unsigned o = __shfl_down(ss, off);
      if (ln + off < 64) ss += o;
    }
    if (ln == 0) wsum[w] = ss;
    __syncthreads();
    unsigned run = ss - ts;
    for (int u = w + 1; u < 4; ++u) run += wsum[u];
#pragma unroll
    for (int b = 7; b >= 0; --b) {
      if (run < (unsigned)rem && run + h[b] >= (unsigned)rem) {
        s_cut = 8 * t + b;
        s_ngt = (int)run;
      }
      run += h[b];
    }
    __syncthreads();
    const int cut = s_cut;
    const int ngt = s_ngt;
    const int incut = (int)hist[cut];
    rem -= ngt;
#pragma unroll
    for (int j = 0; j < 8; ++j) {
      if (!(alive & (1u << j))) continue;
      const int b = (int)((key[j] >> shift) & bmask);
      if (b > cut) { winner |= 1u << j; alive &= ~(1u << j); }
      else if (b < cut) alive &= ~(1u << j);
    }
    if (incut == rem) {
      winner |= alive; alive = 0u; done = 1;
    } else if (level == 2) {
#pragma unroll
      for (int j = 0; j < 8; ++j)
        if (alive & (1u << j)) {
          const int pos = atomicAdd(&s_ntie, 1);
          const int col = (j < 4) ? (4 * t + j) : (1024 + 4 * t + j - 4);
          if (pos < 128) s_tie[pos] = col;
          s_tieval = val[j];
        }
      __syncthreads();
      if (w == 0) {
        volatile int* vt = s_tie;
        const int n = (s_ntie < 128) ? s_ntie : 128;
        const int take = (rem < n) ? rem : n;
        for (int it = 0; it < take; ++it) {
          int c0 = (ln < n) ? vt[ln] : 0x7FFFFFFF;
          int c1 = (ln + 64 < n) ? vt[ln + 64] : 0x7FFFFFFF;
          int bc, bs;
          if (c1 < c0) { bc = c1; bs = ln + 64; } else { bc = c0; bs = ln; }
#pragma unroll
          for (int off = 32; off; off >>= 1) {
            const int oc = __shfl_xor(bc, off);
            const int os = __shfl_xor(bs, off);
            if (oc < bc) { bc = oc; bs = os; }
          }
          if (ln == 0) {
            vt[bs] = 0x7FFFFFFF;
            const int p = s_nw;
            s_wcol[p] = bc; s_wval[p] = s_tieval;
            s_nw = p + 1;
          }
        }
      }
      alive = 0u;
      done = 1;
    }
    __syncthreads();
    if (done) break;
  }

#pragma unroll
  for (int j = 0; j < 8; ++j)
    if (winner & (1u << j)) {
      const int pos = atomicAdd(&s_nw, 1);
      const int col = (j < 4) ? (4 * t + j) : (1024 + 4 * t + j - 4);
      if (pos < kSel) { s_wcol[pos] = col; s_wval[pos] = val[j]; }
    }
  __syncthreads();

  // ---- find worst & second-worst among the 65 (wave 0) ----
  if (w == 0) {
    float wv = s_wval[ln]; int wc2 = s_wcol[ln];
    float sv = 1e30f; int sc = -1;
    if (ln == 0) {
      const float v64 = s_wval[64]; const int c64 = s_wcol[64];
      if (worse(v64, c64, wv, wc2)) { sv = wv; sc = wc2; wv = v64; wc2 = c64; }
      else { sv = v64; sc = c64; }
    }
#pragma unroll
    for (int off = 32; off; off >>= 1) {
      const float owv = __shfl_down(wv, off); const int owc = __shfl_down(wc2, off);
      const float osv = __shfl_down(sv, off); const int osc = __shfl_down(sc, off);
      if (worse(owv, owc, wv, wc2)) {
        const bool x2 = worse(wv, wc2, osv, osc);
        sv = x2 ? wv : osv; sc = x2 ? wc2 : osc;
        wv = owv; wc2 = owc;
      } else {
        const bool x2 = worse(owv, owc, sv, sc);
        sv = x2 ? owv : sv; sc = x2 ? owc : sc;
      }
    }
    if (ln == 0) {
      s_c0 = wc2; s_c1 = sc; s_gap = sv - wv;
      s_excl = wc2;
    }
  }
  __syncthreads();

  // ---- true-fp64 boundary refine (from x, Wq, Wk — round-2-proven block) ----
  if (s_nw == kSel && s_gap < 3e-4f) {
    const int b = row >> 11;
    const int cw = s_c0, cs = s_c1;
    const long xrow = (long)row * kD;
    const long k0r = ((long)(b << 11) + cw) * kD;
    const long k1r = ((long)(b << 11) + cs) * kD;
    for (int d = t; d < kD; d += 256) {
      sxq[d] = x[xrow + d];
      sx0[d] = x[k0r + d];
      sx1[d] = x[k1r + d];
    }
    __syncthreads();
    double p0 = 0.0, p1 = 0.0;
    for (int e = t; e < kD; e += 256) {
      double qe = (double)bq[e], k0e = (double)bk[e], k1e = (double)bk[e];
      const float* wq = Wq + (long)e * kD;
      const float* wk = Wk + (long)e * kD;
      for (int d = 0; d < kD; ++d) {
        qe += (double)sxq[d] * (double)wq[d];
        k0e += (double)sx0[d] * (double)wk[d];
        k1e += (double)sx1[d] * (double)wk[d];
      }
      p0 += qe * k0e;
      p1 += qe * k1e;
    }
#pragma unroll
    for (int off = 32; off; off >>= 1) {
      p0 += __shfl_down(p0, off);
      p1 += __shfl_down(p1, off);
    }
    if (ln == 0) { rd0[w] = p0; rd1[w] = p1; }
    __syncthreads();
    if (t == 0) {
      const double e0 = rd0[0] + rd0[1] + rd0[2] + rd0[3];  // exact score of cw
      const double e1 = rd1[0] + rd1[1] + rd1[2] + rd1[3];  // exact score of cs
      if (e0 > e1 || (e0 == e1 && cw < cs)) s_excl = cs; else s_excl = cw;
    }
    __syncthreads();
  }

  // compact to 64 kept entries
  if (t == 0) s_slot = kSel - 1;
  __syncthreads();
  if (t < kSel && s_wcol[t] == s_excl) s_slot = t;
  __syncthreads();
  if (t < kTopK) {
    const int src = t + (t >= s_slot ? 1 : 0);
    s_kc[t] = s_wcol[src];
    s_kv[t] = s_wval[src];
  }
  __syncthreads();

  // softmax over kept 64 (wave 0)
  if (w == 0) {
    const float v = s_kv[ln];
    float m = v;
#pragma unroll
    for (int off = 32; off; off >>= 1) m = fmaxf(m, __shfl_xor(m, off));
    float p = expf(v - m);
    float Z = p;
#pragma unroll
    for (int off = 32; off; off >>= 1) Z += __shfl_xor(Z, off);
    p /= Z;
    s_kv[ln] = p;
  }
  __syncthreads();

  // dense attn row: fp32 to d_out + bf16 copy for the out-GEMM
  float* lrow = (float*)hist;
  ((float4*)lrow)[t] = make_float4(0.f, 0.f, 0.f, 0.f);
  ((float4*)lrow)[t + 256] = make_float4(0.f, 0.f, 0.f, 0.f);
  __syncthreads();
  if (t < kTopK) lrow[s_kc[t]] = s_kv[t];
  __syncthreads();
  float4* dst = (float4*)(attn + (long)row * kS);
  dst[t] = ((const float4*)lrow)[t];
  dst[t + 256] = ((const float4*)lrow)[t + 256];
  {
    const float* src = lrow + t * 8;
    unsigned short u[8];
#pragma unroll
    for (int j = 0; j < 8; ++j)
      u[j] = __builtin_bit_cast(unsigned short, __float2bfloat16(src[j]));
    const unsigned p0 = (unsigned)u[0] | ((unsigned)u[1] << 16);
    const unsigned p1 = (unsigned)u[2] | ((unsigned)u[3] << 16);
    const unsigned p2 = (unsigned)u[4] | ((unsigned)u[5] << 16);
    const unsigned p3 = (unsigned)u[6] | ((unsigned)u[7] << 16);
    ((uint4*)(attnh + (long)row * kS))[t] = make_uint4(p0, p1, p2, p3);
  }
}

extern "C" void kernel_launch(void* const* d_in, const int* in_sizes, int n_in,
                              void* d_out, int out_size, void* d_ws, size_t ws_size,
                              hipStream_t stream) {
  (void)in_sizes; (void)n_in; (void)out_size; (void)ws_size;
  const float* x = (const float*)d_in[0];
  const float* Wq = (const float*)d_in[1];
  const float* bq = (const float*)d_in[2];
  const float* Wk = (const float*)d_in[3];
  const float* bk = (const float*)d_in[4];
  const float* Wv = (const float*)d_in[5];
  const float* bv = (const float*)d_in[6];
  const float* Wo = (const float*)d_in[7];
  const float* bo = (const float*)d_in[8];

  float* out = (float*)d_out;             // [4,2048,512]
  float* attn = out + (long)kRows * kD;   // [4,2048,2048]

  const size_t SZ_ROWS = (size_t)kRows * kD * 2;    // 8 MB bf16 [8192,512]
  const size_t SZ_W = (size_t)kD * kD * 2;          // 512 KB bf16 [512,512]
  const size_t SZ_ATTNH = (size_t)kRows * kS * 2;   // 33.5 MB bf16 [8192,2048]
  char* ws = (char*)d_ws;

  // region A (67.1 MB): x3 splits first; scores overwrites after VWT (x3 dead)
  bf16* xh = (bf16*)(ws + 0);
  bf16* xm = (bf16*)(ws + SZ_ROWS);
  bf16* xl = (bf16*)(ws + 2 * SZ_ROWS);
  float* scores = (float*)(ws + 0);  // 67108864 B
  size_t off = 67108864;
  auto alloc = [&](size_t bytes) {
    void* p = ws + off;
    off += (bytes + 255) & ~(size_t)255;
    return p;
  };
  bf16* Wqh = (bf16*)alloc(SZ_W); bf16* Wqm = (bf16*)alloc(SZ_W);
  bf16* Wkh = (bf16*)alloc(SZ_W); bf16* Wkm = (bf16*)alloc(SZ_W);
  bf16* Mh = (bf16*)alloc(SZ_W);
  float* cb = (float*)alloc(kD * 4);
  // region C (32 MB): Q/K h+m splits
  bf16* Qh = (bf16*)alloc(SZ_ROWS);
  bf16* Qm = (bf16*)alloc(SZ_ROWS);
  bf16* Kh = (bf16*)alloc(SZ_ROWS);
  bf16* Km = (bf16*)alloc(SZ_ROWS);
  bf16* VWTh = (bf16*)alloc((size_t)kBatch * kD * kS * 2);  // 8.4 MB
  bf16* attnh = (bf16*)alloc(SZ_ATTNH);                     // 33.5 MB

  const float inv_sqrt_d = 1.0f / sqrtf((float)kD);

  // 1. splits + M/cb precompute (Wo,Wv folded into M = Wo@Wv; no V-projection)
  split3<<<2048, 256, 0, stream>>>(x, xh, xm, xl, kRows * kD);
  split2x2<<<dim3(128, 2), 256, 0, stream>>>(Wq, Wqh, Wqm, Wk, Wkh, Wkm, kD * kD);
  precompute_M<<<dim3(8, 8), 256, 0, stream>>>(Wo, Wv, Mh);
  precompute_cb<<<kD, 64, 0, stream>>>(Wo, bv, cb);

  const int LDS_P3 = 2 * 2 * (128 + 64) * 64;   // 49152 (Q/K proj, 3-product)
  const int LDS_V1 = 2 * 1 * (128 + 64) * 64;   // 24576 (VWT, 1-product)
  const int LDS_S3 = 2 * 2 * (256 + 128) * 64;  // 98304 (scores 256x128, 8 waves)
  const int LDS_O1 = 2 * 1 * (128 + 128) * 64;  // 32768 (out GEMM, BN=128)
  const dim3 gP(kD / 64, kRows / 128, 1);         // (8, 64)  = 512 blocks
  const dim3 gVWT(kS / 64, kD / 128, kBatch);     // (32, 4, 4) = 512 blocks
  const dim3 gScore(kS / 128, kS / 256, kBatch);  // (16, 8, 4) = 512 blocks
  const dim3 gOut(kD / 128, kS / 128, kBatch);    // (4, 16, 4) = 256 blocks

  // 2. Q,K projections (3-product now suffices: selection handled by true-fp64
  //    refine; instantiation <2,3,128,64,2,2> is the rounds-8/9-proven V-proj)
  gemm_pipe<2, 3, 128, 64, 2, 2, false><<<gP, 256, LDS_P3, stream>>>(
      xh, xm, nullptr, Wqh, Wqm, nullptr, nullptr, Qh, Qm, nullptr,
      bq, 1.0f, kD, kD, kD, kD, 0, 0, 0);
  gemm_pipe<2, 3, 128, 64, 2, 2, false><<<gP, 256, LDS_P3, stream>>>(
      xh, xm, nullptr, Wkh, Wkm, nullptr, nullptr, Kh, Km, nullptr,
      bk, 1.0f, kD, kD, kD, kD, 0, 0, 0);
  // 3. VWT = Mh @ x^T + cb (1-product) -> bf16 h
  gemm_pipe<3, 1, 128, 64, 2, 2, true><<<gVWT, 256, LDS_V1, stream>>>(
      Mh, nullptr, nullptr, xh, nullptr, nullptr, nullptr, VWTh, nullptr, nullptr,
      cb, 1.0f, kS, kD, kD, kD, 0, (long)kS * kD, (long)kD * kS);
  // 4. scores = (Q @ K^T) * inv_sqrt_d (3-product, 256x128, 512 thr — proven)
  gemm_pipe<0, 3, 256, 128, 4, 2, false><<<gScore, 512, LDS_S3, stream>>>(
      Qh, Qm, nullptr, Kh, Km, nullptr,
      scores, nullptr, nullptr, nullptr, nullptr, inv_sqrt_d, kS, kD, kD, kD,
      (long)kS * kD, (long)kS * kD, (long)kS * kS);
  // 5. top-65 select + true-fp64 boundary refine + softmax + attn fp32/bf16
  topk_kernel<<<kRows, 256, 0, stream>>>(scores, x, Wq, bq, Wk, bk, attn, attnh);
  // 6. out = attn_bf16 @ VWT^T + bo (1-product dense GEMM)
  gemm_pipe<0, 1, 128, 128, 2, 2, false><<<gOut, 256, LDS_O1, stream>>>(
      attnh, nullptr, nullptr, VWTh, nullptr, nullptr,
      out, nullptr, nullptr, nullptr, bo, 1.0f, kD, kS, kS, kS,
      (long)kS * kS, (long)kD * kS, (long)kS * kD);
}

// Round 16
// 248.059 us; speedup vs baseline: 2.2207x; 2.2207x over previous
//
#include <hip/hip_runtime.h>
#include <hip/hip_bf16.h>
#include <math.h>

#define AS1 __attribute__((address_space(1)))
#define AS3 __attribute__((address_space(3)))

typedef __attribute__((ext_vector_type(8))) short bf16x8;
typedef __attribute__((ext_vector_type(4))) float f32x4;
typedef __hip_bfloat16 bf16;

namespace {
constexpr int kBatch = 4, kS = 2048, kD = 512;
constexpr int kRows = kBatch * kS;   // 8192
constexpr int kTopK = 64;
constexpr int kSel = 65;             // select 65, refine the 64/65 boundary
}

__device__ __forceinline__ void async16(void* lds, const void* g) {
  __builtin_amdgcn_global_load_lds((AS1 void*)g, (AS3 void*)lds, 16, 0, 0);
}

template<int N> __device__ __forceinline__ void wait_vm() {
  if constexpr (N == 0) asm volatile("s_waitcnt vmcnt(0)" ::: "memory");
  else if constexpr (N == 3) asm volatile("s_waitcnt vmcnt(3)" ::: "memory");
  else if constexpr (N == 6) asm volatile("s_waitcnt vmcnt(6)" ::: "memory");
  else if constexpr (N == 9) asm volatile("s_waitcnt vmcnt(9)" ::: "memory");
  else static_assert(N == 0, "unsupported vmcnt");
}

// ---------- fp32 -> bf16 h/m/l 3-way split ----------
__global__ __launch_bounds__(256) void split3(
    const float* __restrict__ in, bf16* __restrict__ h, bf16* __restrict__ m,
    bf16* __restrict__ l, int n) {
  int i = blockIdx.x * 256 + threadIdx.x;
  const int stride = gridDim.x * 256;
  for (; i < n; i += stride) {
    const float x = in[i];
    const bf16 hh = __float2bfloat16(x);
    const float r = x - __bfloat162float(hh);
    const bf16 mm = __float2bfloat16(r);
    const float r2 = r - __bfloat162float(mm);
    h[i] = hh; m[i] = mm; l[i] = __float2bfloat16(r2);
  }
}

struct WSplitArgs {
  const float* w[4];
  bf16* h[4]; bf16* m[4]; bf16* l[4];
};
__global__ __launch_bounds__(256) void split3x4(WSplitArgs a, int n) {
  const int g = blockIdx.y;
  const float* in = a.w[g];
  bf16* h = a.h[g]; bf16* m = a.m[g]; bf16* l = a.l[g];
  int i = blockIdx.x * 256 + threadIdx.x;
  const int stride = gridDim.x * 256;
  for (; i < n; i += stride) {
    const float x = in[i];
    const bf16 hh = __float2bfloat16(x);
    const float r = x - __bfloat162float(hh);
    const bf16 mm = __float2bfloat16(r);
    const float r2 = r - __bfloat162float(mm);
    h[i] = hh; m[i] = mm; l[i] = __float2bfloat16(r2);
  }
}

// ---------- pipelined C[M,N] = scale*(A @ B^T) + bias, split-bf16 precision ----------
// PROVEN structure (rounds 5/7/8/9/13/14, passed post-timing): dbuf LDS + counted
// vmcnt, one STAGE + one monolithic COMPUTE per K-step, two raw barriers.
// OUTMODE 0: fp32 C; 1: h/m/l out; 2: h/m out; 3: h out. BIASROW: bias[row].
template<int OUTMODE, int NPROD, int BM, int BN, int WAVES_M, int WAVES_N, bool BIASROW>
__global__ __launch_bounds__(64 * WAVES_M * WAVES_N, 2) void gemm_pipe(
    const bf16* __restrict__ Ah, const bf16* __restrict__ Am, const bf16* __restrict__ Al,
    const bf16* __restrict__ Bh, const bf16* __restrict__ Bm, const bf16* __restrict__ Bl,
    float* __restrict__ C, bf16* __restrict__ Ch, bf16* __restrict__ Cm, bf16* __restrict__ Cl,
    const float* __restrict__ bias, float scale, int N, int K, int lda, int ldb,
    long batchA, long batchB, long batchC) {
  constexpr int NP = (NPROD == 6) ? 3 : (NPROD == 3) ? 2 : 1;
  constexpr int T = 64 * WAVES_M * WAVES_N;
  constexpr int WM = BM / WAVES_M, WN = BN / WAVES_N;
  constexpr int FI = WM / 16, FJ = WN / 16;
  constexpr int ABYTES = BM * 64, BBYTES = BN * 64;
  constexpr int HALF = NP * (ABYTES + BBYTES);
  constexpr int SPAN = T * 16;
  constexpr int CALLS = HALF / SPAN;
  static_assert(HALF % SPAN == 0, "staging must be whole call-spans");
  extern __shared__ char smem[];

  const int t = threadIdx.x;
  const int wi = t >> 6, ln = t & 63;
  const int wr = wi / WAVES_N, wc = wi % WAVES_N;

  int bx, by, bz;
  {
    const int F = blockIdx.x + gridDim.x * (blockIdx.y + gridDim.y * blockIdx.z);
    const int cpx = (gridDim.x * gridDim.y * gridDim.z) >> 3;
    const int L = (F & 7) * cpx + (F >> 3);
    bx = L % gridDim.x;
    const int r = L / gridDim.x;
    by = r % gridDim.y; bz = r / gridDim.y;
  }
  const int m0 = by * BM, n0 = bx * BN;
  const long zA = (long)bz * batchA;
  const long zB = (long)bz * batchB;
  const long zC = (long)bz * batchC;

  const bf16* gp[CALLS];
#pragma unroll
  for (int q = 0; q < CALLS; ++q) {
    const int o = q * SPAN + t * 16;
    const bf16* base; long rbase; int local; int ld;
    if (o < NP * ABYTES) {
      const int p = o / ABYTES; local = o % ABYTES;
      base = (p == 0) ? Ah : (p == 1) ? Am : Al;
      rbase = zA + (long)m0 * lda; ld = lda;
    } else {
      const int o2 = o - NP * ABYTES;
      const int p = o2 / BBYTES; local = o2 % BBYTES;
      base = (p == 0) ? Bh : (p == 1) ? Bm : Bl;
      rbase = zB + (long)n0 * ldb; ld = ldb;
    }
    const int s = local >> 7;
    const int pc = (local >> 4) & 7;
    const int lc = pc ^ (s & 7);
    const int row = 2 * s + (lc >> 2);
    const int ke = (lc & 3) << 3;
    gp[q] = base + rbase + (long)row * ld + ke;
  }
  const int lofs = wi * 1024;

  const int fr = ln & 15, cc = ln >> 4;
  const int c2 = ((fr & 1) << 2) | cc;
  int aoff[FI], boff[FJ];
#pragma unroll
  for (int i = 0; i < FI; ++i) {
    const int s = (wr * WM + i * 16 + fr) >> 1;
    aoff[i] = s * 128 + ((c2 ^ (s & 7)) << 4);
  }
#pragma unroll
  for (int j = 0; j < FJ; ++j) {
    const int s = (wc * WN + j * 16 + fr) >> 1;
    boff[j] = s * 128 + ((c2 ^ (s & 7)) << 4);
  }

  f32x4 acc1[FI][FJ] = {}, acc2[FI][FJ] = {};

  auto STAGE = [&](int buf, int kt) {
#pragma unroll
    for (int q = 0; q < CALLS; ++q)
      async16(smem + buf * HALF + q * SPAN + lofs, gp[q] + kt);
  };

  auto COMPUTE = [&](const char* rb) {
    bf16x8 AH[FI], BH[FJ], AX[FI], BX[FJ];
#pragma unroll
    for (int i = 0; i < FI; ++i) AH[i] = *(const bf16x8*)(rb + aoff[i]);
#pragma unroll
    for (int j = 0; j < FJ; ++j) BH[j] = *(const bf16x8*)(rb + NP * ABYTES + boff[j]);
#pragma unroll
    for (int i = 0; i < FI; ++i)
#pragma unroll
      for (int j = 0; j < FJ; ++j)
        acc1[i][j] = __builtin_amdgcn_mfma_f32_16x16x32_bf16(AH[i], BH[j], acc1[i][j], 0, 0, 0);
    if constexpr (NPROD == 6) {
#pragma unroll
      for (int i = 0; i < FI; ++i) AX[i] = *(const bf16x8*)(rb + 2 * ABYTES + aoff[i]);
#pragma unroll
      for (int j = 0; j < FJ; ++j) BX[j] = *(const bf16x8*)(rb + NP * ABYTES + 2 * BBYTES + boff[j]);
#pragma unroll
      for (int i = 0; i < FI; ++i)
#pragma unroll
        for (int j = 0; j < FJ; ++j) {
          acc2[i][j] = __builtin_amdgcn_mfma_f32_16x16x32_bf16(AH[i], BX[j], acc2[i][j], 0, 0, 0);
          acc2[i][j] = __builtin_amdgcn_mfma_f32_16x16x32_bf16(AX[i], BH[j], acc2[i][j], 0, 0, 0);
        }
    }
    if constexpr (NPROD >= 3) {
#pragma unroll
      for (int i = 0; i < FI; ++i) AX[i] = *(const bf16x8*)(rb + 1 * ABYTES + aoff[i]);
#pragma unroll
      for (int j = 0; j < FJ; ++j) BX[j] = *(const bf16x8*)(rb + NP * ABYTES + 1 * BBYTES + boff[j]);
#pragma unroll
      for (int i = 0; i < FI; ++i)
#pragma unroll
        for (int j = 0; j < FJ; ++j) {
          acc2[i][j] = __builtin_amdgcn_mfma_f32_16x16x32_bf16(AH[i], BX[j], acc2[i][j], 0, 0, 0);
          acc2[i][j] = __builtin_amdgcn_mfma_f32_16x16x32_bf16(AX[i], BH[j], acc2[i][j], 0, 0, 0);
          if constexpr (NPROD == 6)
            acc2[i][j] = __builtin_amdgcn_mfma_f32_16x16x32_bf16(AX[i], BX[j], acc2[i][j], 0, 0, 0);
        }
    }
  };

  STAGE(0, 0);
  int cur = 0;
  for (int kt = 32; kt < K; kt += 32) {
    STAGE(cur ^ 1, kt);
    wait_vm<CALLS>();
    __builtin_amdgcn_s_barrier();
    COMPUTE(smem + cur * HALF);
    asm volatile("s_waitcnt lgkmcnt(0)" ::: "memory");
    __builtin_amdgcn_s_barrier();
    cur ^= 1;
  }
  wait_vm<0>();
  __builtin_amdgcn_s_barrier();
  COMPUTE(smem + cur * HALF);

  const int fc = ln & 15;
  const int fr4 = (ln >> 4) << 2;
#pragma unroll
  for (int i = 0; i < FI; ++i) {
    const int rbase = m0 + wr * WM + i * 16 + fr4;
#pragma unroll
    for (int j = 0; j < FJ; ++j) {
      const int c = n0 + wc * WN + j * 16 + fc;
#pragma unroll
      for (int q = 0; q < 4; ++q) {
        const float bb = bias ? (BIASROW ? bias[rbase + q] : bias[c]) : 0.0f;
        const float val = (acc1[i][j][q] + acc2[i][j][q]) * scale + bb;
        const long off = zC + (long)(rbase + q) * N + c;
        if constexpr (OUTMODE == 0) {
          C[off] = val;
        } else if constexpr (OUTMODE == 1) {
          const bf16 h = __float2bfloat16(val);
          const float r = val - __bfloat162float(h);
          const bf16 m = __float2bfloat16(r);
          Ch[off] = h; Cm[off] = m;
          Cl[off] = __float2bfloat16(r - __bfloat162float(m));
        } else if constexpr (OUTMODE == 2) {
          const bf16 h = __float2bfloat16(val);
          Ch[off] = h;
          Cm[off] = __float2bfloat16(val - __bfloat162float(h));
        } else {
          Ch[off] = __float2bfloat16(val);
        }
      }
    }
  }
}

// ---------- radix-select top-65 + fp64 split-based boundary refine + softmax + attn ----------
__device__ __forceinline__ unsigned f2key(float f) {
  const unsigned u = __float_as_uint(f);
  return (u & 0x80000000u) ? ~u : (u | 0x80000000u);
}
__device__ __forceinline__ bool worse(float av, int ac, float bv, int bc) {
  return (av < bv) || (av == bv && ac > bc);
}

__global__ __launch_bounds__(256) void topk_kernel(
    const float* __restrict__ scores,
    const bf16* __restrict__ Qh, const bf16* __restrict__ Qm, const bf16* __restrict__ Ql,
    const bf16* __restrict__ Kh, const bf16* __restrict__ Km, const bf16* __restrict__ Kl,
    float* __restrict__ attn, bf16* __restrict__ attnh) {
  const int row = blockIdx.x;  // 0..8191
  const int t = threadIdx.x, ln = t & 63, w = t >> 6;
  const float* srow = scores + (long)row * kS;

  __shared__ __align__(16) unsigned hist[2048];
  __shared__ float s_wval[kSel];
  __shared__ int s_wcol[kSel];
  __shared__ float s_kv[kTopK];
  __shared__ int s_kc[kTopK];
  __shared__ unsigned wsum[4];
  __shared__ int s_cut, s_ngt, s_nw, s_ntie;
  __shared__ int s_tie[128];
  __shared__ float s_tieval;
  __shared__ int s_c0, s_c1, s_excl, s_slot;
  __shared__ float s_gap;
  __shared__ double rd0[4], rd1[4];

  if (t == 0) { s_nw = 0; s_ntie = 0; }

  float val[8]; unsigned key[8];
  {
    const float4 q0 = ((const float4*)srow)[t];
    const float4 q1 = ((const float4*)srow)[t + 256];
    val[0] = q0.x; val[1] = q0.y; val[2] = q0.z; val[3] = q0.w;
    val[4] = q1.x; val[5] = q1.y; val[6] = q1.z; val[7] = q1.w;
  }
#pragma unroll
  for (int j = 0; j < 8; ++j) key[j] = f2key(val[j]);

  unsigned alive = 0xFFu, winner = 0u;
  int rem = kSel, done = 0;

  for (int level = 0; level < 3; ++level) {
    const int shift = (level == 0) ? 21 : (level == 1) ? 10 : 0;
    const unsigned bmask = (level == 2) ? 0x3FFu : 0x7FFu;
    for (int i = t; i < 2048; i += 256) hist[i] = 0u;
    __syncthreads();
#pragma unroll
    for (int j = 0; j < 8; ++j)
      if (alive & (1u << j)) atomicAdd(&hist[(key[j] >> shift) & bmask], 1u);
    __syncthreads();

    unsigned h[8]; unsigned ts = 0u;
#pragma unroll
    for (int b = 0; b < 8; ++b) { h[b] = hist[8 * t + b]; ts += h[b]; }
    unsigned ss = ts;
#pragma unroll
    for (int off = 1; off < 64; off <<= 1) {
      const unsigned o = __shfl_down(ss, off);
      if (ln + off < 64) ss += o;
    }
    if (ln == 0) wsum[w] = ss;
    __syncthreads();
    unsigned run = ss - ts;
    for (int u = w + 1; u < 4; ++u) run += wsum[u];
#pragma unroll
    for (int b = 7; b >= 0; --b) {
      if (run < (unsigned)rem && run + h[b] >= (unsigned)rem) {
        s_cut = 8 * t + b;
        s_ngt = (int)run;
      }
      run += h[b];
    }
    __syncthreads();
    const int cut = s_cut;
    const int ngt = s_ngt;
    const int incut = (int)hist[cut];
    rem -= ngt;
#pragma unroll
    for (int j = 0; j < 8; ++j) {
      if (!(alive & (1u << j))) continue;
      const int b = (int)((key[j] >> shift) & bmask);
      if (b > cut) { winner |= 1u << j; alive &= ~(1u << j); }
      else if (b < cut) alive &= ~(1u << j);
    }
    if (incut == rem) {
      winner |= alive; alive = 0u; done = 1;
    } else if (level == 2) {
#pragma unroll
      for (int j = 0; j < 8; ++j)
        if (alive & (1u << j)) {
          const int pos = atomicAdd(&s_ntie, 1);
          const int col = (j < 4) ? (4 * t + j) : (1024 + 4 * t + j - 4);
          if (pos < 128) s_tie[pos] = col;
          s_tieval = val[j];
        }
      __syncthreads();
      if (w == 0) {
        volatile int* vt = s_tie;
        const int n = (s_ntie < 128) ? s_ntie : 128;
        const int take = (rem < n) ? rem : n;
        for (int it = 0; it < take; ++it) {
          int c0 = (ln < n) ? vt[ln] : 0x7FFFFFFF;
          int c1 = (ln + 64 < n) ? vt[ln + 64] : 0x7FFFFFFF;
          int bc, bs;
          if (c1 < c0) { bc = c1; bs = ln + 64; } else { bc = c0; bs = ln; }
#pragma unroll
          for (int off = 32; off; off >>= 1) {
            const int oc = __shfl_xor(bc, off);
            const int os = __shfl_xor(bs, off);
            if (oc < bc) { bc = oc; bs = os; }
          }
          if (ln == 0) {
            vt[bs] = 0x7FFFFFFF;
            const int p = s_nw;
            s_wcol[p] = bc; s_wval[p] = s_tieval;
            s_nw = p + 1;
          }
        }
      }
      alive = 0u;
      done = 1;
    }
    __syncthreads();
    if (done) break;
  }

#pragma unroll
  for (int j = 0; j < 8; ++j)
    if (winner & (1u << j)) {
      const int pos = atomicAdd(&s_nw, 1);
      const int col = (j < 4) ? (4 * t + j) : (1024 + 4 * t + j - 4);
      if (pos < kSel) { s_wcol[pos] = col; s_wval[pos] = val[j]; }
    }
  __syncthreads();

  // ---- find worst & second-worst among the 65 (wave 0) ----
  if (w == 0) {
    float wv = s_wval[ln]; int wc2 = s_wcol[ln];
    float sv = 1e30f; int sc = -1;
    if (ln == 0) {
      const float v64 = s_wval[64]; const int c64 = s_wcol[64];
      if (worse(v64, c64, wv, wc2)) { sv = wv; sc = wc2; wv = v64; wc2 = c64; }
      else { sv = v64; sc = c64; }
    }
#pragma unroll
    for (int off = 32; off; off >>= 1) {
      const float owv = __shfl_down(wv, off); const int owc = __shfl_down(wc2, off);
      const float osv = __shfl_down(sv, off); const int osc = __shfl_down(sc, off);
      if (worse(owv, owc, wv, wc2)) {
        const bool x = worse(wv, wc2, osv, osc);
        sv = x ? wv : osv; sc = x ? wc2 : osc;
        wv = owv; wc2 = owc;
      } else {
        const bool x = worse(owv, owc, sv, sc);
        sv = x ? owv : sv; sc = x ? owc : sc;
      }
    }
    if (ln == 0) {
      s_c0 = wc2; s_c1 = sc; s_gap = sv - wv;
      s_excl = wc2;
    }
  }
  __syncthreads();

  // ---- fp64 boundary refine from stored h/m/l splits (cheap, coalesced) ----
  if (s_nw == kSel && s_gap < 3e-4f) {
    const int b = row >> 11;
    const int cw = s_c0, cs = s_c1;
    const long qoff = (long)row * kD;
    const long k0off = ((long)(b << 11) + cw) * kD;
    const long k1off = ((long)(b << 11) + cs) * kD;
    double p0 = 0.0, p1 = 0.0;
    const unsigned qhp = ((const unsigned*)(Qh + qoff))[t];
    const unsigned qmp = ((const unsigned*)(Qm + qoff))[t];
    const unsigned qlp = ((const unsigned*)(Ql + qoff))[t];
    const unsigned k0h = ((const unsigned*)(Kh + k0off))[t];
    const unsigned k0m = ((const unsigned*)(Km + k0off))[t];
    const unsigned k0l = ((const unsigned*)(Kl + k0off))[t];
    const unsigned k1h = ((const unsigned*)(Kh + k1off))[t];
    const unsigned k1m = ((const unsigned*)(Km + k1off))[t];
    const unsigned k1l = ((const unsigned*)(Kl + k1off))[t];
    auto bflo = [](unsigned u) { return __uint_as_float(u << 16); };
    auto bfhi = [](unsigned u) { return __uint_as_float(u & 0xFFFF0000u); };
    {
      const double q0 = (double)bflo(qhp) + (double)bflo(qmp) + (double)bflo(qlp);
      const double q1 = (double)bfhi(qhp) + (double)bfhi(qmp) + (double)bfhi(qlp);
      const double a0 = (double)bflo(k0h) + (double)bflo(k0m) + (double)bflo(k0l);
      const double a1 = (double)bfhi(k0h) + (double)bfhi(k0m) + (double)bfhi(k0l);
      const double b0 = (double)bflo(k1h) + (double)bflo(k1m) + (double)bflo(k1l);
      const double b1 = (double)bfhi(k1h) + (double)bfhi(k1m) + (double)bfhi(k1l);
      p0 = q0 * a0 + q1 * a1;
      p1 = q0 * b0 + q1 * b1;
    }
#pragma unroll
    for (int off = 32; off; off >>= 1) {
      p0 += __shfl_down(p0, off);
      p1 += __shfl_down(p1, off);
    }
    if (ln == 0) { rd0[w] = p0; rd1[w] = p1; }
    __syncthreads();
    if (t == 0) {
      const double e0 = rd0[0] + rd0[1] + rd0[2] + rd0[3];
      const double e1 = rd1[0] + rd1[1] + rd1[2] + rd1[3];
      if (e0 > e1 || (e0 == e1 && cw < cs)) s_excl = cs; else s_excl = cw;
    }
    __syncthreads();
  }

  // compact to 64 kept entries
  if (t == 0) s_slot = kSel - 1;
  __syncthreads();
  if (t < kSel && s_wcol[t] == s_excl) s_slot = t;
  __syncthreads();
  if (t < kTopK) {
    const int src = t + (t >= s_slot ? 1 : 0);
    s_kc[t] = s_wcol[src];
    s_kv[t] = s_wval[src];
  }
  __syncthreads();

  // softmax over kept 64 (wave 0)
  if (w == 0) {
    const float v = s_kv[ln];
    float m = v;
#pragma unroll
    for (int off = 32; off; off >>= 1) m = fmaxf(m, __shfl_xor(m, off));
    float p = expf(v - m);
    float Z = p;
#pragma unroll
    for (int off = 32; off; off >>= 1) Z += __shfl_xor(Z, off);
    p /= Z;
    s_kv[ln] = p;
  }
  __syncthreads();

  // dense attn row: fp32 to d_out + bf16 copy for the out-GEMM
  float* lrow = (float*)hist;
  ((float4*)lrow)[t] = make_float4(0.f, 0.f, 0.f, 0.f);
  ((float4*)lrow)[t + 256] = make_float4(0.f, 0.f, 0.f, 0.f);
  __syncthreads();
  if (t < kTopK) lrow[s_kc[t]] = s_kv[t];
  __syncthreads();
  float4* dst = (float4*)(attn + (long)row * kS);
  dst[t] = ((const float4*)lrow)[t];
  dst[t + 256] = ((const float4*)lrow)[t + 256];
  {
    const float* src = lrow + t * 8;
    unsigned short u[8];
#pragma unroll
    for (int j = 0; j < 8; ++j)
      u[j] = __builtin_bit_cast(unsigned short, __float2bfloat16(src[j]));
    const unsigned p0 = (unsigned)u[0] | ((unsigned)u[1] << 16);
    const unsigned p1 = (unsigned)u[2] | ((unsigned)u[3] << 16);
    const unsigned p2 = (unsigned)u[4] | ((unsigned)u[5] << 16);
    const unsigned p3 = (unsigned)u[6] | ((unsigned)u[7] << 16);
    ((uint4*)(attnh + (long)row * kS))[t] = make_uint4(p0, p1, p2, p3);
  }
}

extern "C" void kernel_launch(void* const* d_in, const int* in_sizes, int n_in,
                              void* d_out, int out_size, void* d_ws, size_t ws_size,
                              hipStream_t stream) {
  (void)in_sizes; (void)n_in; (void)out_size; (void)ws_size;
  const float* x = (const float*)d_in[0];
  const float* Wq = (const float*)d_in[1];
  const float* bq = (const float*)d_in[2];
  const float* Wk = (const float*)d_in[3];
  const float* bk = (const float*)d_in[4];
  const float* Wv = (const float*)d_in[5];
  const float* bv = (const float*)d_in[6];
  const float* Wo = (const float*)d_in[7];
  const float* bo = (const float*)d_in[8];

  float* out = (float*)d_out;             // [4,2048,512]
  float* attn = out + (long)kRows * kD;   // [4,2048,2048]

  const size_t SZ_ROWS = (size_t)kRows * kD * 2;    // 8 MB bf16 [8192,512]
  const size_t SZ_W = (size_t)kD * kD * 2;          // 512 KB bf16 [512,512]
  const size_t SZ_ATTNH = (size_t)kRows * kS * 2;   // 33.5 MB bf16 [8192,2048]
  char* ws = (char*)d_ws;

  // region A (67.1 MB): x3 splits first, then scores overwrites (x3 dead by then)
  bf16* xh = (bf16*)(ws + 0);
  bf16* xm = (bf16*)(ws + SZ_ROWS);
  bf16* xl = (bf16*)(ws + 2 * SZ_ROWS);
  float* scores = (float*)(ws + 0);  // 67108864 B
  size_t off = 67108864;
  auto alloc = [&](size_t bytes) {
    void* p = ws + off;
    off += (bytes + 255) & ~(size_t)255;
    return p;
  };
  bf16* Wqh = (bf16*)alloc(SZ_W); bf16* Wqm = (bf16*)alloc(SZ_W); bf16* Wql = (bf16*)alloc(SZ_W);
  bf16* Wkh = (bf16*)alloc(SZ_W); bf16* Wkm = (bf16*)alloc(SZ_W); bf16* Wkl = (bf16*)alloc(SZ_W);
  bf16* Wvh = (bf16*)alloc(SZ_W); bf16* Wvm = (bf16*)alloc(SZ_W);
  bf16* Woh = (bf16*)alloc(SZ_W); bf16* Wom = (bf16*)alloc(SZ_W);
  bf16* Wvl = (bf16*)alloc(SZ_W); bf16* Wol = (bf16*)alloc(SZ_W);
  // region C (48 MB): Q3,K3 splits (live through topk for the refine)
  char* regC = (char*)alloc(6 * SZ_ROWS);
  bf16* Qh = (bf16*)(regC);
  bf16* Qm = (bf16*)(regC + SZ_ROWS);
  bf16* Ql = (bf16*)(regC + 2 * SZ_ROWS);
  bf16* Kh = (bf16*)(regC + 3 * SZ_ROWS);
  bf16* Km = (bf16*)(regC + 4 * SZ_ROWS);
  bf16* Kl = (bf16*)(regC + 5 * SZ_ROWS);
  // VWT bf16 [4][512][2048] (8.4 MB), persistent to the final GEMM
  bf16* VWTh = (bf16*)alloc((size_t)kBatch * kD * kS * 2);
  // V h (8 MB), dead after the VWT GEMM -> attnh aliases from Vh
  bf16* Vh = (bf16*)alloc(SZ_ROWS);
  bf16* Vm = (bf16*)alloc(SZ_ROWS);
  alloc(SZ_ATTNH - 2 * SZ_ROWS);   // extend region so attnh fits
  bf16* attnh = Vh;                // alias: V dead before topk writes attnh

  const float inv_sqrt_d = 1.0f / sqrtf((float)kD);

  // 1. splits
  split3<<<2048, 256, 0, stream>>>(x, xh, xm, xl, kRows * kD);
  {
    WSplitArgs a;
    a.w[0] = Wq; a.w[1] = Wk; a.w[2] = Wv; a.w[3] = Wo;
    a.h[0] = Wqh; a.h[1] = Wkh; a.h[2] = Wvh; a.h[3] = Woh;
    a.m[0] = Wqm; a.m[1] = Wkm; a.m[2] = Wvm; a.m[3] = Wom;
    a.l[0] = Wql; a.l[1] = Wkl; a.l[2] = Wvl; a.l[3] = Wol;
    split3x4<<<dim3(128, 4), 256, 0, stream>>>(a, kD * kD);
  }

  const int LDS_P6 = 2 * 3 * (128 + 64) * 64;   // 73728
  const int LDS_P3 = 2 * 2 * (128 + 64) * 64;   // 49152
  const int LDS_S3 = 2 * 2 * (256 + 128) * 64;  // 98304 (scores, 3-product)
  const int LDS_1P = 2 * 1 * (128 + 64) * 64;   // 24576 (VWT / out, 1-product)
  const dim3 gP(kD / 64, kRows / 128, 1);         // 512 blocks
  const dim3 gScore(kS / 128, kS / 256, kBatch);  // 512 blocks
  const dim3 gVWT(kS / 64, kD / 128, kBatch);     // (32, 4, 4) = 512 blocks
  const dim3 gOut(kD / 64, kS / 128, kBatch);     // (8, 16, 4) = 512 blocks

  // 2. Q,K projections (6-product) -> h/m/l (l feeds the split-based refine)
  gemm_pipe<1, 6, 128, 64, 2, 2, false><<<gP, 256, LDS_P6, stream>>>(
      xh, xm, xl, Wqh, Wqm, Wql, nullptr, Qh, Qm, Ql,
      bq, 1.0f, kD, kD, kD, kD, 0, 0, 0);
  gemm_pipe<1, 6, 128, 64, 2, 2, false><<<gP, 256, LDS_P6, stream>>>(
      xh, xm, xl, Wkh, Wkm, Wkl, nullptr, Kh, Km, Kl,
      bk, 1.0f, kD, kD, kD, kD, 0, 0, 0);
  // 3. V projection (3-product) -> bf16 h only (includes bv)
  gemm_pipe<3, 3, 128, 64, 2, 2, false><<<gP, 256, LDS_P3, stream>>>(
      xh, xm, nullptr, Wvh, Wvm, nullptr, nullptr, Vh, nullptr, nullptr,
      bv, 1.0f, kD, kD, kD, kD, 0, 0, 0);
  // 4. VWT[b][e][c] = sum_d Wo[e][d] V[b][c][d] (1-product: VWTh bf16 anyway)
  gemm_pipe<3, 1, 128, 64, 2, 2, false><<<gVWT, 256, LDS_1P, stream>>>(
      Woh, nullptr, nullptr, Vh, nullptr, nullptr, nullptr, VWTh, nullptr, nullptr,
      nullptr, 1.0f, kS, kD, kD, kD, 0, (long)kS * kD, (long)kD * kS);
  // 5. scores = (Q @ K^T) * inv_sqrt_d (3-product, 256x128, 512 thr — proven)
  gemm_pipe<0, 3, 256, 128, 4, 2, false><<<gScore, 512, LDS_S3, stream>>>(
      Qh, Qm, nullptr, Kh, Km, nullptr,
      scores, nullptr, nullptr, nullptr, nullptr, inv_sqrt_d, kS, kD, kD, kD,
      (long)kS * kD, (long)kS * kD, (long)kS * kS);
  // 6. top-65 select + split-based fp64 refine + softmax + attn fp32 + attn bf16
  topk_kernel<<<kRows, 256, 0, stream>>>(scores, Qh, Qm, Ql, Kh, Km, Kl, attn, attnh);
  // 7. out = attn_bf16 @ VWT^T + bo (1-product dense GEMM, round-9 config)
  gemm_pipe<0, 1, 128, 64, 2, 2, false><<<gOut, 256, LDS_1P, stream>>>(
      attnh, nullptr, nullptr, VWTh, nullptr, nullptr,
      out, nullptr, nullptr, nullptr, bo, 1.0f, kD, kS, kS, kS,
      (long)kS * kS, (long)kD * kS, (long)kS * kD);
}